// Round 1
// baseline (837.417 us; speedup 1.0000x reference)
//
#include <hip/hip_runtime.h>
#include <stdint.h>
#include <stddef.h>

#define D_HID 2304
#define NTOK  8192          // 4 * 2048
#define NQKV  6912          // 3 * 2304
#define WELEMS 5308416      // 2304*2304
#define SEQ_MASK 2047

typedef unsigned short u16;
typedef __bf16 bf16x8 __attribute__((ext_vector_type(8)));
typedef float  f32x4  __attribute__((ext_vector_type(4)));

__device__ __forceinline__ u16 f2bf(float f) {
    unsigned int u = __builtin_bit_cast(unsigned int, f);
    u += 0x7fffu + ((u >> 16) & 1u);           // RNE
    return (u16)(u >> 16);
}
__device__ __forceinline__ float bf2f(u16 h) {
    unsigned int u = ((unsigned int)h) << 16;
    return __builtin_bit_cast(float, u);
}

__device__ __forceinline__ void gl2lds16(const void* g, void* l) {
    __builtin_amdgcn_global_load_lds(
        (const __attribute__((address_space(1))) void*)g,
        (__attribute__((address_space(3))) void*)l,
        16, 0, 0);
}

// ---------------------------------------------------------------- converts
__global__ __launch_bounds__(256) void cvt_f32_bf16(
    const float* __restrict__ src, u16* __restrict__ dst)
{
    size_t i = ((size_t)blockIdx.x * 256 + threadIdx.x) * 4;
    float4 f = *(const float4*)(src + i);
    ushort4 o = make_ushort4(f2bf(f.x), f2bf(f.y), f2bf(f.z), f2bf(f.w));
    *(ushort4*)(dst + i) = o;
}

// converts wq,wk,wv,wo (each 2304x2304, row-major, K-contiguous) into one
// contiguous bf16 buffer [wq|wk|wv|wo]; also builds the fused qkv bias.
__global__ __launch_bounds__(256) void cvt_weights(
    const float* __restrict__ wq, const float* __restrict__ wk,
    const float* __restrict__ wv, const float* __restrict__ wo,
    u16* __restrict__ dst,
    const float* __restrict__ bq, const float* __restrict__ bk,
    const float* __restrict__ bv, float* __restrict__ bqkv)
{
    int i = blockIdx.x * 256 + threadIdx.x;
    if (i < NQKV)
        bqkv[i] = (i < 2304) ? bq[i] : (i < 4608) ? bk[i - 2304] : bv[i - 4608];
    size_t base = (size_t)i * 4;                 // grid sized exactly: 4*WELEMS elems
    int r = (int)(base / WELEMS);
    const float* src = (r == 0) ? wq : (r == 1) ? wk : (r == 2) ? wv : wo;
    float4 f = *(const float4*)(src + (base - (size_t)r * WELEMS));
    ushort4 o = make_ushort4(f2bf(f.x), f2bf(f.y), f2bf(f.z), f2bf(f.w));
    *(ushort4*)(dst + base) = o;
}

// ---------------------------------------------------------------- GEMM
// C[M,N] = A[M,K] * B[N,K]^T  (both K-major, bf16), fp32 accumulate.
// MODE 0: C = acc + bias        -> bf16 out
// MODE 1: C = acc + bias + res  -> fp32 out
// 128x128 tile, BK=32, 4 waves in 2x2, each wave 64x64 via 4x4 MFMA 16x16x32.
template<int MODE>
__global__ __launch_bounds__(256) void gemm_bt(
    const u16* __restrict__ A, const u16* __restrict__ B,
    const float* __restrict__ bias, void* __restrict__ Cout,
    const float* __restrict__ resid, int M, int N, int K)
{
    __shared__ __align__(16) u16 As[128 * 32];
    __shared__ __align__(16) u16 Bs[128 * 32];

    const int tid  = threadIdx.x;
    const int lane = tid & 63;
    const int wave = tid >> 6;
    const int bm = blockIdx.y, bn = blockIdx.x;

    // staging: each thread loads 16B (8 bf16); 256 thr cover 64 rows x 32 cols
    const u16* Ag = A + (size_t)(bm * 128 + (tid >> 2)) * K + (tid & 3) * 8;
    const u16* Bg = B + (size_t)(bn * 128 + (tid >> 2)) * K + (tid & 3) * 8;
    const size_t off64 = (size_t)64 * K;
    // lds dest: wave-uniform base; HW adds lane*16B. row-major 128x32, no pad.
    u16* asd0 = As + wave * 512;
    u16* asd1 = As + 2048 + wave * 512;
    u16* bsd0 = Bs + wave * 512;
    u16* bsd1 = Bs + 2048 + wave * 512;

    const int fr = lane & 15;      // row within 16 (A: m, B: n)
    const int fq = lane >> 4;      // quad -> k-chunk
    const int wm = (wave >> 1) * 64;
    const int wn = (wave & 1) * 64;

    f32x4 acc[4][4] = {};

    for (int kb = 0; kb < K; kb += 32) {
        __syncthreads();
        gl2lds16(Ag + kb,         asd0);
        gl2lds16(Ag + kb + off64, asd1);
        gl2lds16(Bg + kb,         bsd0);
        gl2lds16(Bg + kb + off64, bsd1);
        __syncthreads();

        bf16x8 af[4], bfr[4];
#pragma unroll
        for (int i = 0; i < 4; ++i)
            af[i] = *(const bf16x8*)(As + (wm + i * 16 + fr) * 32 + fq * 8);
#pragma unroll
        for (int j = 0; j < 4; ++j)
            bfr[j] = *(const bf16x8*)(Bs + (wn + j * 16 + fr) * 32 + fq * 8);
#pragma unroll
        for (int i = 0; i < 4; ++i)
#pragma unroll
            for (int j = 0; j < 4; ++j)
                acc[i][j] = __builtin_amdgcn_mfma_f32_16x16x32_bf16(
                    af[i], bfr[j], acc[i][j], 0, 0, 0);
    }

    // epilogue: C/D layout col = lane&15, row = quad*4 + reg
#pragma unroll
    for (int i = 0; i < 4; ++i) {
#pragma unroll
        for (int j = 0; j < 4; ++j) {
            const int gn = bn * 128 + wn + j * 16 + fr;
            const float bv = bias[gn];
#pragma unroll
            for (int r = 0; r < 4; ++r) {
                const int gm = bm * 128 + wm + i * 16 + fq * 4 + r;
                const size_t idx = (size_t)gm * N + gn;
                float v = acc[i][j][r] + bv;
                if constexpr (MODE == 0) {
                    ((u16*)Cout)[idx] = f2bf(v);
                } else {
                    ((float*)Cout)[idx] = v + resid[idx];
                }
            }
        }
    }
}

// ---------------------------------------------------------------- attention
// One block per token. RoPE (full 2304 dim) fused into LDS staging of q,k.
// Head-mix: S[16][16] = Q K^T / 12, softmax over m, O = S V. Out bf16.
__global__ __launch_bounds__(256) void attn_headmix(
    const u16* __restrict__ QKV, u16* __restrict__ Aout)
{
    __shared__ __align__(16) float qs[D_HID];
    __shared__ __align__(16) float ks[D_HID];
    __shared__ __align__(16) float vs[D_HID];
    __shared__ float wsm[256];

    const int tid = threadIdx.x;
    const int t   = blockIdx.x;
    const float fpos = (float)(t & SEQ_MASK);
    const u16* row = QKV + (size_t)t * NQKV;

    const float OMEGA_C = -2.0f * 13.287712379549449f / 2304.0f; // -2*log2(1e4)/d
    const float INV2PI  = 0.15915494309189535f;

    for (int c = tid; c < 864; c += 256) {       // 864 chunks of 8 bf16
        uint4 raw = *(const uint4*)(row + c * 8);
        float f[8];
        f[0] = bf2f(raw.x & 0xffff); f[1] = bf2f(raw.x >> 16);
        f[2] = bf2f(raw.y & 0xffff); f[3] = bf2f(raw.y >> 16);
        f[4] = bf2f(raw.z & 0xffff); f[5] = bf2f(raw.z >> 16);
        f[6] = bf2f(raw.w & 0xffff); f[7] = bf2f(raw.w >> 16);
        if (c < 576) {                            // q or k chunk -> RoPE
            const int cc = (c < 288) ? c : c - 288;
            const int p0 = cc * 4;                // pair index base
#pragma unroll
            for (int jp = 0; jp < 4; ++jp) {
                float omega = exp2f((float)(p0 + jp) * OMEGA_C);
                float rr = fpos * omega * INV2PI;
                rr -= floorf(rr);
                float sn = __builtin_amdgcn_sinf(rr);  // sin(2*pi*rr)
                float cs = __builtin_amdgcn_cosf(rr);
                float x0 = f[2 * jp], x1 = f[2 * jp + 1];
                f[2 * jp]     = cs * x0 - sn * x1;
                f[2 * jp + 1] = sn * x0 + cs * x1;
            }
            float* dst = ((c < 288) ? qs : ks) + cc * 8;
            *(float4*)(dst)     = make_float4(f[0], f[1], f[2], f[3]);
            *(float4*)(dst + 4) = make_float4(f[4], f[5], f[6], f[7]);
        } else {
            float* dst = vs + (c - 576) * 8;
            *(float4*)(dst)     = make_float4(f[0], f[1], f[2], f[3]);
            *(float4*)(dst + 4) = make_float4(f[4], f[5], f[6], f[7]);
        }
    }
    __syncthreads();

    // S[n][m]: thread (n = tid>>4, m = tid&15)
    const int n = tid >> 4, m = tid & 15;
    const float* qr = qs + n * 144;
    const float* kr = ks + m * 144;
    float s = 0.f;
#pragma unroll
    for (int d = 0; d < 144; d += 4) {
        float4 qv = *(const float4*)(qr + d);
        float4 kv = *(const float4*)(kr + d);
        s += qv.x * kv.x + qv.y * kv.y + qv.z * kv.z + qv.w * kv.w;
    }
    s *= (1.0f / 12.0f);                         // 1/sqrt(144)

    // softmax over m: 16-lane groups (16-aligned, masks<16 stay in group)
    float mx = s;
#pragma unroll
    for (int off = 8; off >= 1; off >>= 1) mx = fmaxf(mx, __shfl_xor(mx, off));
    float e = __expf(s - mx);
    float sum = e;
#pragma unroll
    for (int off = 8; off >= 1; off >>= 1) sum += __shfl_xor(sum, off);
    wsm[tid] = e / sum;
    __syncthreads();

    // O[n][d] = sum_m w[n][m] * v[m][d]; 2304 outputs, 9 per thread
    u16* orow = Aout + (size_t)t * D_HID;
#pragma unroll
    for (int r = 0; r < 9; ++r) {
        int o  = tid + r * 256;
        int on = o / 144;
        int od = o - on * 144;
        const float* wrow = wsm + on * 16;
        const float* vcol = vs + od;
        float a = 0.f;
#pragma unroll
        for (int mm = 0; mm < 16; ++mm) a += wrow[mm] * vcol[mm * 144];
        orow[o] = f2bf(a);
    }
}

// ---------------------------------------------------------------- layernorm
__global__ __launch_bounds__(256) void ln_kernel(
    const float* __restrict__ Y, const float* __restrict__ g,
    const float* __restrict__ b, float* __restrict__ out)
{
    const int tid  = threadIdx.x;
    const float* y = Y + (size_t)blockIdx.x * D_HID;
    float v[9];
    float s = 0.f, s2 = 0.f;
#pragma unroll
    for (int r = 0; r < 9; ++r) {
        v[r] = y[tid + r * 256];
        s += v[r]; s2 += v[r] * v[r];
    }
#pragma unroll
    for (int off = 32; off >= 1; off >>= 1) {
        s  += __shfl_xor(s, off);
        s2 += __shfl_xor(s2, off);
    }
    __shared__ float red[8];
    const int wave = tid >> 6;
    if ((tid & 63) == 0) { red[wave] = s; red[4 + wave] = s2; }
    __syncthreads();
    s  = red[0] + red[1] + red[2] + red[3];
    s2 = red[4] + red[5] + red[6] + red[7];
    const float inv_n = 1.0f / 2304.0f;
    float mu  = s * inv_n;
    float var = fmaxf(s2 * inv_n - mu * mu, 0.f);
    float inv = rsqrtf(var + 1e-5f);
    float* orow = out + (size_t)blockIdx.x * D_HID;
#pragma unroll
    for (int r = 0; r < 9; ++r) {
        int c = tid + r * 256;
        orow[c] = (v[r] - mu) * inv * g[c] + b[c];
    }
}

// ---------------------------------------------------------------- launch
extern "C" void kernel_launch(void* const* d_in, const int* in_sizes, int n_in,
                              void* d_out, int out_size, void* d_ws, size_t ws_size,
                              hipStream_t stream)
{
    const float* x   = (const float*)d_in[0];
    const float* wq  = (const float*)d_in[1];
    const float* bq  = (const float*)d_in[2];
    const float* wk  = (const float*)d_in[3];
    const float* bk  = (const float*)d_in[4];
    const float* wv  = (const float*)d_in[5];
    const float* bv  = (const float*)d_in[6];
    const float* wo  = (const float*)d_in[7];
    const float* bo  = (const float*)d_in[8];
    const float* lng = (const float*)d_in[9];
    const float* lnb = (const float*)d_in[10];

    char* ws = (char*)d_ws;
    size_t off = 0;
    auto alloc = [&](size_t bytes) {
        void* p = ws + off;
        off += (bytes + 255) & ~(size_t)255;
        return p;
    };
    u16*   xb   = (u16*)alloc((size_t)NTOK * D_HID * 2);        // 37.75 MB
    u16*   wqkv = (u16*)alloc((size_t)(NQKV + D_HID) * D_HID * 2); // 42.5 MB (wqkv+wo)
    u16*   wob  = wqkv + (size_t)NQKV * D_HID;
    float* bqkv = (float*)alloc((size_t)NQKV * 4);
    u16*   qkv  = (u16*)alloc((size_t)NTOK * NQKV * 2);         // 113.25 MB
    u16*   aout = (u16*)alloc((size_t)NTOK * D_HID * 2);        // 37.75 MB
    float* ybuf = (float*)qkv;  // QKV dead after attention; reuse for fp32 y

    // total ws use ~231 MB

    cvt_f32_bf16<<<NTOK * D_HID / 1024, 256, 0, stream>>>(x, xb);
    cvt_weights<<<4 * WELEMS / 1024, 256, 0, stream>>>(wq, wk, wv, wo, wqkv,
                                                       bq, bk, bv, bqkv);
    gemm_bt<0><<<dim3(NQKV / 128, NTOK / 128), 256, 0, stream>>>(
        xb, wqkv, bqkv, qkv, nullptr, NTOK, NQKV, D_HID);
    attn_headmix<<<NTOK, 256, 0, stream>>>(qkv, aout);
    gemm_bt<1><<<dim3(D_HID / 128, NTOK / 128), 256, 0, stream>>>(
        aout, wob, bo, ybuf, x, NTOK, D_HID, D_HID);
    ln_kernel<<<NTOK, 256, 0, stream>>>(ybuf, lng, lnb, (float*)d_out);
}

// Round 2
// 791.816 us; speedup vs baseline: 1.0576x; 1.0576x over previous
//
#include <hip/hip_runtime.h>
#include <stdint.h>
#include <stddef.h>

#define D_HID 2304
#define NTOK  8192          // 4 * 2048
#define NQKV  6912          // 3 * 2304
#define WELEMS 5308416      // 2304*2304
#define SEQ_MASK 2047

typedef unsigned short u16;
typedef __bf16 bf16x8 __attribute__((ext_vector_type(8)));
typedef float  f32x16 __attribute__((ext_vector_type(16)));

__device__ __forceinline__ u16 f2bf(float f) {
    unsigned int u = __builtin_bit_cast(unsigned int, f);
    u += 0x7fffu + ((u >> 16) & 1u);           // RNE
    return (u16)(u >> 16);
}
__device__ __forceinline__ float bf2f(u16 h) {
    unsigned int u = ((unsigned int)h) << 16;
    return __builtin_bit_cast(float, u);
}

__device__ __forceinline__ void gl2lds16(const void* g, void* l) {
    __builtin_amdgcn_global_load_lds(
        (const __attribute__((address_space(1))) void*)g,
        (__attribute__((address_space(3))) void*)l,
        16, 0, 0);
}

// ---------------------------------------------------------------- converts
__global__ __launch_bounds__(256) void cvt_f32_bf16(
    const float* __restrict__ src, u16* __restrict__ dst)
{
    size_t i = ((size_t)blockIdx.x * 256 + threadIdx.x) * 4;
    float4 f = *(const float4*)(src + i);
    ushort4 o = make_ushort4(f2bf(f.x), f2bf(f.y), f2bf(f.z), f2bf(f.w));
    *(ushort4*)(dst + i) = o;
}

__global__ __launch_bounds__(256) void cvt_weights(
    const float* __restrict__ wq, const float* __restrict__ wk,
    const float* __restrict__ wv, const float* __restrict__ wo,
    u16* __restrict__ dst,
    const float* __restrict__ bq, const float* __restrict__ bk,
    const float* __restrict__ bv, float* __restrict__ bqkv)
{
    int i = blockIdx.x * 256 + threadIdx.x;
    if (i < NQKV)
        bqkv[i] = (i < 2304) ? bq[i] : (i < 4608) ? bk[i - 2304] : bv[i - 4608];
    size_t base = (size_t)i * 4;
    int r = (int)(base / WELEMS);
    const float* src = (r == 0) ? wq : (r == 1) ? wk : (r == 2) ? wv : wo;
    float4 f = *(const float4*)(src + (base - (size_t)r * WELEMS));
    ushort4 o = make_ushort4(f2bf(f.x), f2bf(f.y), f2bf(f.z), f2bf(f.w));
    *(ushort4*)(dst + base) = o;
}

// ---------------------------------------------------------------- GEMM
// C[M,N] = A[M,K] * B[N,K]^T  (both K-major, bf16), fp32 accumulate.
// 128x128 tile, BK=32, 4 waves 2x2, each wave 64x64 via 2x2 MFMA 32x32x16.
// LDS layout XOR-swizzled: row r, 16B-chunk slot c' holds global chunk
// c = c' ^ ((r>>1)&3)  -> every 8 consecutive lanes of a ds_read_b128 cover
// all 8 bank-groups (conflict-free).
// MODE 0: C = acc + bias         -> bf16 out
// MODE 1: C = acc + bias + resid -> bf16 out (resid fp32)
template<int MODE>
__global__ __launch_bounds__(256) void gemm_bt(
    const u16* __restrict__ A, const u16* __restrict__ B,
    const float* __restrict__ bias, u16* __restrict__ Cout,
    const float* __restrict__ resid, int M, int N, int K)
{
    __shared__ __align__(16) u16 As[128 * 32];
    __shared__ __align__(16) u16 Bs[128 * 32];

    const int tid  = threadIdx.x;
    const int lane = tid & 63;
    const int wave = tid >> 6;
    const int bm = blockIdx.y, bn = blockIdx.x;

    // staging: thread loads 16B; source chunk permuted to realize the swizzle
    const int srow = tid >> 2;                        // 0..63 within a 64-row half
    const int sc   = (tid & 3) ^ ((tid >> 3) & 3);    // (tid>>3)&3 == (srow>>1)&3
    const u16* Ag = A + (size_t)(bm * 128 + srow) * K + sc * 8;
    const u16* Bg = B + (size_t)(bn * 128 + srow) * K + sc * 8;
    const size_t off64 = (size_t)64 * K;
    u16* asd0 = As + wave * 512;
    u16* asd1 = As + 2048 + wave * 512;
    u16* bsd0 = Bs + wave * 512;
    u16* bsd1 = Bs + 2048 + wave * 512;

    const int rl = lane & 31;      // row within 32-tile (A: m, B: n)
    const int h  = lane >> 5;      // k-half
    const int sw = (rl >> 1) & 3;  // XOR swizzle key
    const int wm = (wave >> 1) * 64;
    const int wn = (wave & 1) * 64;

    // precomputed u16-offsets into As/Bs for frag (tile, k-step)
    int a_off[2][2], b_off[2][2];
#pragma unroll
    for (int t = 0; t < 2; ++t)
#pragma unroll
        for (int s = 0; s < 2; ++s) {
            const int ch = ((s * 2 + h) ^ sw) * 8;    // u16 units (16B chunk)
            a_off[t][s] = (wm + t * 32 + rl) * 32 + ch;
            b_off[t][s] = (wn + t * 32 + rl) * 32 + ch;
        }

    f32x16 acc[2][2] = {};

    for (int kb = 0; kb < K; kb += 32) {
        __syncthreads();
        gl2lds16(Ag + kb,         asd0);
        gl2lds16(Ag + kb + off64, asd1);
        gl2lds16(Bg + kb,         bsd0);
        gl2lds16(Bg + kb + off64, bsd1);
        __syncthreads();

        bf16x8 af[2][2], bf[2][2];
#pragma unroll
        for (int t = 0; t < 2; ++t)
#pragma unroll
            for (int s = 0; s < 2; ++s) {
                af[t][s] = *(const bf16x8*)(As + a_off[t][s]);
                bf[t][s] = *(const bf16x8*)(Bs + b_off[t][s]);
            }
#pragma unroll
        for (int s = 0; s < 2; ++s)
#pragma unroll
            for (int mt = 0; mt < 2; ++mt)
#pragma unroll
                for (int nt = 0; nt < 2; ++nt)
                    acc[mt][nt] = __builtin_amdgcn_mfma_f32_32x32x16_bf16(
                        af[mt][s], bf[nt][s], acc[mt][nt], 0, 0, 0);
    }

    // epilogue: C/D layout col = lane&31, row = (reg&3) + 8*(reg>>2) + 4*h
#pragma unroll
    for (int mt = 0; mt < 2; ++mt) {
#pragma unroll
        for (int nt = 0; nt < 2; ++nt) {
            const int gn = bn * 128 + wn + nt * 32 + rl;
            const float bv = bias[gn];
#pragma unroll
            for (int reg = 0; reg < 16; ++reg) {
                const int gm = bm * 128 + wm + mt * 32 +
                               (reg & 3) + 8 * (reg >> 2) + 4 * h;
                const size_t idx = (size_t)gm * N + gn;
                float v = acc[mt][nt][reg] + bv;
                if constexpr (MODE == 1) v += resid[idx];
                Cout[idx] = f2bf(v);
            }
        }
    }
}

// ---------------------------------------------------------------- attention
__global__ __launch_bounds__(256) void attn_headmix(
    const u16* __restrict__ QKV, u16* __restrict__ Aout)
{
    __shared__ __align__(16) float qs[D_HID];
    __shared__ __align__(16) float ks[D_HID];
    __shared__ __align__(16) float vs[D_HID];
    __shared__ float wsm[256];

    const int tid = threadIdx.x;
    const int t   = blockIdx.x;
    const float fpos = (float)(t & SEQ_MASK);
    const u16* row = QKV + (size_t)t * NQKV;

    const float OMEGA_C = -2.0f * 13.287712379549449f / 2304.0f; // -2*log2(1e4)/d
    const float INV2PI  = 0.15915494309189535f;

    for (int c = tid; c < 864; c += 256) {
        uint4 raw = *(const uint4*)(row + c * 8);
        float f[8];
        f[0] = bf2f(raw.x & 0xffff); f[1] = bf2f(raw.x >> 16);
        f[2] = bf2f(raw.y & 0xffff); f[3] = bf2f(raw.y >> 16);
        f[4] = bf2f(raw.z & 0xffff); f[5] = bf2f(raw.z >> 16);
        f[6] = bf2f(raw.w & 0xffff); f[7] = bf2f(raw.w >> 16);
        if (c < 576) {
            const int cc = (c < 288) ? c : c - 288;
            const int p0 = cc * 4;
#pragma unroll
            for (int jp = 0; jp < 4; ++jp) {
                float omega = exp2f((float)(p0 + jp) * OMEGA_C);
                float rr = fpos * omega * INV2PI;
                rr -= floorf(rr);
                float sn = __builtin_amdgcn_sinf(rr);
                float cs = __builtin_amdgcn_cosf(rr);
                float x0 = f[2 * jp], x1 = f[2 * jp + 1];
                f[2 * jp]     = cs * x0 - sn * x1;
                f[2 * jp + 1] = sn * x0 + cs * x1;
            }
            float* dst = ((c < 288) ? qs : ks) + cc * 8;
            *(float4*)(dst)     = make_float4(f[0], f[1], f[2], f[3]);
            *(float4*)(dst + 4) = make_float4(f[4], f[5], f[6], f[7]);
        } else {
            float* dst = vs + (c - 576) * 8;
            *(float4*)(dst)     = make_float4(f[0], f[1], f[2], f[3]);
            *(float4*)(dst + 4) = make_float4(f[4], f[5], f[6], f[7]);
        }
    }
    __syncthreads();

    const int n = tid >> 4, m = tid & 15;
    const float* qr = qs + n * 144;
    const float* kr = ks + m * 144;
    float s = 0.f;
#pragma unroll
    for (int d = 0; d < 144; d += 4) {
        float4 qv = *(const float4*)(qr + d);
        float4 kv = *(const float4*)(kr + d);
        s += qv.x * kv.x + qv.y * kv.y + qv.z * kv.z + qv.w * kv.w;
    }
    s *= (1.0f / 12.0f);

    float mx = s;
#pragma unroll
    for (int off = 8; off >= 1; off >>= 1) mx = fmaxf(mx, __shfl_xor(mx, off));
    float e = __expf(s - mx);
    float sum = e;
#pragma unroll
    for (int off = 8; off >= 1; off >>= 1) sum += __shfl_xor(sum, off);
    wsm[tid] = e / sum;
    __syncthreads();

    u16* orow = Aout + (size_t)t * D_HID;
#pragma unroll
    for (int r = 0; r < 9; ++r) {
        int o  = tid + r * 256;
        int on = o / 144;
        int od = o - on * 144;
        const float* wrow = wsm + on * 16;
        const float* vcol = vs + od;
        float a = 0.f;
#pragma unroll
        for (int mm = 0; mm < 16; ++mm) a += wrow[mm] * vcol[mm * 144];
        orow[o] = f2bf(a);
    }
}

// ---------------------------------------------------------------- layernorm
__global__ __launch_bounds__(256) void ln_kernel(
    const u16* __restrict__ Y, const float* __restrict__ g,
    const float* __restrict__ b, float* __restrict__ out)
{
    const int tid  = threadIdx.x;
    const u16* y = Y + (size_t)blockIdx.x * D_HID;
    float v[9];
    float s = 0.f, s2 = 0.f;
#pragma unroll
    for (int r = 0; r < 9; ++r) {
        v[r] = bf2f(y[tid + r * 256]);
        s += v[r]; s2 += v[r] * v[r];
    }
#pragma unroll
    for (int off = 32; off >= 1; off >>= 1) {
        s  += __shfl_xor(s, off);
        s2 += __shfl_xor(s2, off);
    }
    __shared__ float red[8];
    const int wave = tid >> 6;
    if ((tid & 63) == 0) { red[wave] = s; red[4 + wave] = s2; }
    __syncthreads();
    s  = red[0] + red[1] + red[2] + red[3];
    s2 = red[4] + red[5] + red[6] + red[7];
    const float inv_n = 1.0f / 2304.0f;
    float mu  = s * inv_n;
    float var = fmaxf(s2 * inv_n - mu * mu, 0.f);
    float inv = rsqrtf(var + 1e-5f);
    float* orow = out + (size_t)blockIdx.x * D_HID;
#pragma unroll
    for (int r = 0; r < 9; ++r) {
        int c = tid + r * 256;
        orow[c] = (v[r] - mu) * inv * g[c] + b[c];
    }
}

// ---------------------------------------------------------------- launch
extern "C" void kernel_launch(void* const* d_in, const int* in_sizes, int n_in,
                              void* d_out, int out_size, void* d_ws, size_t ws_size,
                              hipStream_t stream)
{
    const float* x   = (const float*)d_in[0];
    const float* wq  = (const float*)d_in[1];
    const float* bq  = (const float*)d_in[2];
    const float* wk  = (const float*)d_in[3];
    const float* bk  = (const float*)d_in[4];
    const float* wv  = (const float*)d_in[5];
    const float* bv  = (const float*)d_in[6];
    const float* wo  = (const float*)d_in[7];
    const float* bo  = (const float*)d_in[8];
    const float* lng = (const float*)d_in[9];
    const float* lnb = (const float*)d_in[10];

    char* ws = (char*)d_ws;
    size_t off = 0;
    auto alloc = [&](size_t bytes) {
        void* p = ws + off;
        off += (bytes + 255) & ~(size_t)255;
        return p;
    };
    u16*   xb   = (u16*)alloc((size_t)NTOK * D_HID * 2);
    u16*   wqkv = (u16*)alloc((size_t)(NQKV + D_HID) * D_HID * 2);
    u16*   wob  = wqkv + (size_t)NQKV * D_HID;
    float* bqkv = (float*)alloc((size_t)NQKV * 4);
    u16*   qkv  = (u16*)alloc((size_t)NTOK * NQKV * 2);
    u16*   aout = (u16*)alloc((size_t)NTOK * D_HID * 2);
    u16*   ybuf = qkv;  // QKV dead after attention; reuse for bf16 y

    cvt_f32_bf16<<<NTOK * D_HID / 1024, 256, 0, stream>>>(x, xb);
    cvt_weights<<<4 * WELEMS / 1024, 256, 0, stream>>>(wq, wk, wv, wo, wqkv,
                                                       bq, bk, bv, bqkv);
    gemm_bt<0><<<dim3(NQKV / 128, NTOK / 128), 256, 0, stream>>>(
        xb, wqkv, bqkv, qkv, nullptr, NTOK, NQKV, D_HID);
    attn_headmix<<<NTOK, 256, 0, stream>>>(qkv, aout);
    gemm_bt<1><<<dim3(D_HID / 128, NTOK / 128), 256, 0, stream>>>(
        aout, wob, bo, ybuf, x, NTOK, D_HID, D_HID);
    ln_kernel<<<NTOK, 256, 0, stream>>>(ybuf, lng, lnb, (float*)d_out);
}

// Round 3
// 745.964 us; speedup vs baseline: 1.1226x; 1.0615x over previous
//
#include <hip/hip_runtime.h>
#include <stdint.h>
#include <stddef.h>

#define D_HID 2304
#define NTOK  8192          // 4 * 2048
#define NQKV  6912          // 3 * 2304
#define WELEMS 5308416      // 2304*2304
#define SEQ_MASK 2047

typedef unsigned short u16;
typedef __bf16 bf16x8 __attribute__((ext_vector_type(8)));
typedef float  f32x16 __attribute__((ext_vector_type(16)));

__device__ __forceinline__ u16 f2bf(float f) {
    unsigned int u = __builtin_bit_cast(unsigned int, f);
    u += 0x7fffu + ((u >> 16) & 1u);           // RNE
    return (u16)(u >> 16);
}
__device__ __forceinline__ float bf2f(u16 h) {
    unsigned int u = ((unsigned int)h) << 16;
    return __builtin_bit_cast(float, u);
}

__device__ __forceinline__ void gl2lds16(const void* g, void* l) {
    __builtin_amdgcn_global_load_lds(
        (const __attribute__((address_space(1))) void*)g,
        (__attribute__((address_space(3))) void*)l,
        16, 0, 0);
}

// ---------------------------------------------------------------- converts
__global__ __launch_bounds__(256) void cvt_f32_bf16(
    const float* __restrict__ src, u16* __restrict__ dst)
{
    size_t i = ((size_t)blockIdx.x * 256 + threadIdx.x) * 4;
    float4 f = *(const float4*)(src + i);
    ushort4 o = make_ushort4(f2bf(f.x), f2bf(f.y), f2bf(f.z), f2bf(f.w));
    *(ushort4*)(dst + i) = o;
}

__global__ __launch_bounds__(256) void cvt_weights(
    const float* __restrict__ wq, const float* __restrict__ wk,
    const float* __restrict__ wv, const float* __restrict__ wo,
    u16* __restrict__ dst,
    const float* __restrict__ bq, const float* __restrict__ bk,
    const float* __restrict__ bv, float* __restrict__ bqkv)
{
    int i = blockIdx.x * 256 + threadIdx.x;
    if (i < NQKV)
        bqkv[i] = (i < 2304) ? bq[i] : (i < 4608) ? bk[i - 2304] : bv[i - 4608];
    size_t base = (size_t)i * 4;
    int r = (int)(base / WELEMS);
    const float* src = (r == 0) ? wq : (r == 1) ? wk : (r == 2) ? wv : wo;
    float4 f = *(const float4*)(src + (base - (size_t)r * WELEMS));
    ushort4 o = make_ushort4(f2bf(f.x), f2bf(f.y), f2bf(f.z), f2bf(f.w));
    *(ushort4*)(dst + base) = o;
}

// ---------------------------------------------------------------- GEMM
// C[M,N] = A[M,K] * B[N,K]^T  (both K-major, bf16), fp32 accumulate.
// 128x128 tile, BK=64, 4 waves 2x2, each wave 64x64 via 2x2 MFMA 32x32x16.
// LDS: row-major 128 x 64 u16 (128 B row = one full bank sweep). 16B chunk
// slot c' of row r holds global chunk c = c' ^ (r&7) -> every 8-lane phase
// of a ds_read_b128 covers all 8 bank-groups (conflict-free).
// MODE 0: C = acc + bias         -> bf16 out
// MODE 1: C = acc + bias + resid -> bf16 out (resid fp32)
template<int MODE>
__global__ __launch_bounds__(256, 3) void gemm_bt(
    const u16* __restrict__ A, const u16* __restrict__ B,
    const float* __restrict__ bias, u16* __restrict__ Cout,
    const float* __restrict__ resid, int M, int N, int K)
{
    __shared__ __align__(16) u16 As[128 * 64];
    __shared__ __align__(16) u16 Bs[128 * 64];

    const int tid  = threadIdx.x;
    const int lane = tid & 63;
    const int wave = tid >> 6;
    const int bm = blockIdx.y, bn = blockIdx.x;

    // staging: 256 thr x 16B = 4KB/round = 32 rows; 4 rounds per matrix.
    // thread -> row (tid>>3) in round 0 (+32/round), source chunk swizzled.
    const int srow = tid >> 3;                        // 0..31
    const int sc   = (tid & 7) ^ (srow & 7);          // swizzle key = row&7
    const u16* Ag = A + (size_t)(bm * 128 + srow) * K + sc * 8;
    const u16* Bg = B + (size_t)(bn * 128 + srow) * K + sc * 8;
    const size_t row32 = (size_t)32 * K;
    u16* asd = As + wave * 512;                       // +r*2048 per round
    u16* bsd = Bs + wave * 512;

    const int rl = lane & 31;      // row within 32-tile (A: m, B: n)
    const int h  = lane >> 5;      // k-half of 16-k step
    const int swz = rl & 7;        // read-side swizzle key
    const int wm = (wave >> 1) * 64;
    const int wn = (wave & 1) * 64;

    f32x16 acc[2][2] = {};

    for (int kb = 0; kb < K; kb += 64) {
        __syncthreads();
#pragma unroll
        for (int r = 0; r < 4; ++r) {
            gl2lds16(Ag + kb + r * row32, asd + r * 2048);
            gl2lds16(Bg + kb + r * row32, bsd + r * 2048);
        }
        __syncthreads();

#pragma unroll
        for (int s = 0; s < 4; ++s) {                 // four 16-k steps
            const int ch = ((s * 2 + h) ^ swz) * 8;   // u16 offset of chunk
            bf16x8 a0 = *(const bf16x8*)(As + (wm      + rl) * 64 + ch);
            bf16x8 a1 = *(const bf16x8*)(As + (wm + 32 + rl) * 64 + ch);
            bf16x8 b0 = *(const bf16x8*)(Bs + (wn      + rl) * 64 + ch);
            bf16x8 b1 = *(const bf16x8*)(Bs + (wn + 32 + rl) * 64 + ch);
            acc[0][0] = __builtin_amdgcn_mfma_f32_32x32x16_bf16(a0, b0, acc[0][0], 0, 0, 0);
            acc[0][1] = __builtin_amdgcn_mfma_f32_32x32x16_bf16(a0, b1, acc[0][1], 0, 0, 0);
            acc[1][0] = __builtin_amdgcn_mfma_f32_32x32x16_bf16(a1, b0, acc[1][0], 0, 0, 0);
            acc[1][1] = __builtin_amdgcn_mfma_f32_32x32x16_bf16(a1, b1, acc[1][1], 0, 0, 0);
        }
    }

    // epilogue: C/D layout col = lane&31, row = (reg&3) + 8*(reg>>2) + 4*h
#pragma unroll
    for (int mt = 0; mt < 2; ++mt) {
#pragma unroll
        for (int nt = 0; nt < 2; ++nt) {
            const int gn = bn * 128 + wn + nt * 32 + rl;
            const float bv = bias[gn];
#pragma unroll
            for (int reg = 0; reg < 16; ++reg) {
                const int gm = bm * 128 + wm + mt * 32 +
                               (reg & 3) + 8 * (reg >> 2) + 4 * h;
                const size_t idx = (size_t)gm * N + gn;
                float v = acc[mt][nt][reg] + bv;
                if constexpr (MODE == 1) v += resid[idx];
                Cout[idx] = f2bf(v);
            }
        }
    }
}

// ---------------------------------------------------------------- attention
__global__ __launch_bounds__(256) void attn_headmix(
    const u16* __restrict__ QKV, u16* __restrict__ Aout)
{
    __shared__ __align__(16) float qs[D_HID];
    __shared__ __align__(16) float ks[D_HID];
    __shared__ __align__(16) float vs[D_HID];
    __shared__ float wsm[256];

    const int tid = threadIdx.x;
    const int t   = blockIdx.x;
    const float fpos = (float)(t & SEQ_MASK);
    const u16* row = QKV + (size_t)t * NQKV;

    const float OMEGA_C = -2.0f * 13.287712379549449f / 2304.0f; // -2*log2(1e4)/d
    const float INV2PI  = 0.15915494309189535f;

    for (int c = tid; c < 864; c += 256) {
        uint4 raw = *(const uint4*)(row + c * 8);
        float f[8];
        f[0] = bf2f(raw.x & 0xffff); f[1] = bf2f(raw.x >> 16);
        f[2] = bf2f(raw.y & 0xffff); f[3] = bf2f(raw.y >> 16);
        f[4] = bf2f(raw.z & 0xffff); f[5] = bf2f(raw.z >> 16);
        f[6] = bf2f(raw.w & 0xffff); f[7] = bf2f(raw.w >> 16);
        if (c < 576) {
            const int cc = (c < 288) ? c : c - 288;
            const int p0 = cc * 4;
#pragma unroll
            for (int jp = 0; jp < 4; ++jp) {
                float omega = exp2f((float)(p0 + jp) * OMEGA_C);
                float rr = fpos * omega * INV2PI;
                rr -= floorf(rr);
                float sn = __builtin_amdgcn_sinf(rr);
                float cs = __builtin_amdgcn_cosf(rr);
                float x0 = f[2 * jp], x1 = f[2 * jp + 1];
                f[2 * jp]     = cs * x0 - sn * x1;
                f[2 * jp + 1] = sn * x0 + cs * x1;
            }
            float* dst = ((c < 288) ? qs : ks) + cc * 8;
            *(float4*)(dst)     = make_float4(f[0], f[1], f[2], f[3]);
            *(float4*)(dst + 4) = make_float4(f[4], f[5], f[6], f[7]);
        } else {
            float* dst = vs + (c - 576) * 8;
            *(float4*)(dst)     = make_float4(f[0], f[1], f[2], f[3]);
            *(float4*)(dst + 4) = make_float4(f[4], f[5], f[6], f[7]);
        }
    }
    __syncthreads();

    const int n = tid >> 4, m = tid & 15;
    const float* qr = qs + n * 144;
    const float* kr = ks + m * 144;
    float s = 0.f;
#pragma unroll
    for (int d = 0; d < 144; d += 4) {
        float4 qv = *(const float4*)(qr + d);
        float4 kv = *(const float4*)(kr + d);
        s += qv.x * kv.x + qv.y * kv.y + qv.z * kv.z + qv.w * kv.w;
    }
    s *= (1.0f / 12.0f);

    float mx = s;
#pragma unroll
    for (int off = 8; off >= 1; off >>= 1) mx = fmaxf(mx, __shfl_xor(mx, off));
    float e = __expf(s - mx);
    float sum = e;
#pragma unroll
    for (int off = 8; off >= 1; off >>= 1) sum += __shfl_xor(sum, off);
    wsm[tid] = e / sum;
    __syncthreads();

    u16* orow = Aout + (size_t)t * D_HID;
#pragma unroll
    for (int r = 0; r < 9; ++r) {
        int o  = tid + r * 256;
        int on = o / 144;
        int od = o - on * 144;
        const float* wrow = wsm + on * 16;
        const float* vcol = vs + od;
        float a = 0.f;
#pragma unroll
        for (int mm = 0; mm < 16; ++mm) a += wrow[mm] * vcol[mm * 144];
        orow[o] = f2bf(a);
    }
}

// ---------------------------------------------------------------- layernorm
__global__ __launch_bounds__(256) void ln_kernel(
    const u16* __restrict__ Y, const float* __restrict__ g,
    const float* __restrict__ b, float* __restrict__ out)
{
    const int tid  = threadIdx.x;
    const u16* y = Y + (size_t)blockIdx.x * D_HID;
    float v[9];
    float s = 0.f, s2 = 0.f;
#pragma unroll
    for (int r = 0; r < 9; ++r) {
        v[r] = bf2f(y[tid + r * 256]);
        s += v[r]; s2 += v[r] * v[r];
    }
#pragma unroll
    for (int off = 32; off >= 1; off >>= 1) {
        s  += __shfl_xor(s, off);
        s2 += __shfl_xor(s2, off);
    }
    __shared__ float red[8];
    const int wave = tid >> 6;
    if ((tid & 63) == 0) { red[wave] = s; red[4 + wave] = s2; }
    __syncthreads();
    s  = red[0] + red[1] + red[2] + red[3];
    s2 = red[4] + red[5] + red[6] + red[7];
    const float inv_n = 1.0f / 2304.0f;
    float mu  = s * inv_n;
    float var = fmaxf(s2 * inv_n - mu * mu, 0.f);
    float inv = rsqrtf(var + 1e-5f);
    float* orow = out + (size_t)blockIdx.x * D_HID;
#pragma unroll
    for (int r = 0; r < 9; ++r) {
        int c = tid + r * 256;
        orow[c] = (v[r] - mu) * inv * g[c] + b[c];
    }
}

// ---------------------------------------------------------------- launch
extern "C" void kernel_launch(void* const* d_in, const int* in_sizes, int n_in,
                              void* d_out, int out_size, void* d_ws, size_t ws_size,
                              hipStream_t stream)
{
    const float* x   = (const float*)d_in[0];
    const float* wq  = (const float*)d_in[1];
    const float* bq  = (const float*)d_in[2];
    const float* wk  = (const float*)d_in[3];
    const float* bk  = (const float*)d_in[4];
    const float* wv  = (const float*)d_in[5];
    const float* bv  = (const float*)d_in[6];
    const float* wo  = (const float*)d_in[7];
    const float* bo  = (const float*)d_in[8];
    const float* lng = (const float*)d_in[9];
    const float* lnb = (const float*)d_in[10];

    char* ws = (char*)d_ws;
    size_t off = 0;
    auto alloc = [&](size_t bytes) {
        void* p = ws + off;
        off += (bytes + 255) & ~(size_t)255;
        return p;
    };
    u16*   xb   = (u16*)alloc((size_t)NTOK * D_HID * 2);
    u16*   wqkv = (u16*)alloc((size_t)(NQKV + D_HID) * D_HID * 2);
    u16*   wob  = wqkv + (size_t)NQKV * D_HID;
    float* bqkv = (float*)alloc((size_t)NQKV * 4);
    u16*   qkv  = (u16*)alloc((size_t)NTOK * NQKV * 2);
    u16*   aout = (u16*)alloc((size_t)NTOK * D_HID * 2);
    u16*   ybuf = qkv;  // QKV dead after attention; reuse for bf16 y

    cvt_f32_bf16<<<NTOK * D_HID / 1024, 256, 0, stream>>>(x, xb);
    cvt_weights<<<4 * WELEMS / 1024, 256, 0, stream>>>(wq, wk, wv, wo, wqkv,
                                                       bq, bk, bv, bqkv);
    gemm_bt<0><<<dim3(NQKV / 128, NTOK / 128), 256, 0, stream>>>(
        xb, wqkv, bqkv, qkv, nullptr, NTOK, NQKV, D_HID);
    attn_headmix<<<NTOK, 256, 0, stream>>>(qkv, aout);
    gemm_bt<1><<<dim3(D_HID / 128, NTOK / 128), 256, 0, stream>>>(
        aout, wob, bo, ybuf, x, NTOK, D_HID, D_HID);
    ln_kernel<<<NTOK, 256, 0, stream>>>(ybuf, lng, lnb, (float*)d_out);
}

// Round 4
// 694.303 us; speedup vs baseline: 1.2061x; 1.0744x over previous
//
#include <hip/hip_runtime.h>
#include <stdint.h>
#include <stddef.h>

#define D_HID 2304
#define NTOK  8192          // 4 * 2048
#define NQKV  6912          // 3 * 2304
#define WELEMS 5308416      // 2304*2304
#define SEQ_MASK 2047

typedef unsigned short u16;
typedef __bf16 bf16x8 __attribute__((ext_vector_type(8)));
typedef float  f32x16 __attribute__((ext_vector_type(16)));

__device__ __forceinline__ u16 f2bf(float f) {
    unsigned int u = __builtin_bit_cast(unsigned int, f);
    u += 0x7fffu + ((u >> 16) & 1u);           // RNE
    return (u16)(u >> 16);
}
__device__ __forceinline__ float bf2f(u16 h) {
    unsigned int u = ((unsigned int)h) << 16;
    return __builtin_bit_cast(float, u);
}

__device__ __forceinline__ void gl2lds16(const void* g, void* l) {
    __builtin_amdgcn_global_load_lds(
        (const __attribute__((address_space(1))) void*)g,
        (__attribute__((address_space(3))) void*)l,
        16, 0, 0);
}

// ---------------------------------------------------------------- converts
__global__ __launch_bounds__(256) void cvt_f32_bf16(
    const float* __restrict__ src, u16* __restrict__ dst)
{
    size_t i = ((size_t)blockIdx.x * 256 + threadIdx.x) * 4;
    float4 f = *(const float4*)(src + i);
    ushort4 o = make_ushort4(f2bf(f.x), f2bf(f.y), f2bf(f.z), f2bf(f.w));
    *(ushort4*)(dst + i) = o;
}

__global__ __launch_bounds__(256) void cvt_weights(
    const float* __restrict__ wq, const float* __restrict__ wk,
    const float* __restrict__ wv, const float* __restrict__ wo,
    u16* __restrict__ dst,
    const float* __restrict__ bq, const float* __restrict__ bk,
    const float* __restrict__ bv, float* __restrict__ bqkv)
{
    int i = blockIdx.x * 256 + threadIdx.x;
    if (i < NQKV)
        bqkv[i] = (i < 2304) ? bq[i] : (i < 4608) ? bk[i - 2304] : bv[i - 4608];
    size_t base = (size_t)i * 4;
    int r = (int)(base / WELEMS);
    const float* src = (r == 0) ? wq : (r == 1) ? wk : (r == 2) ? wv : wo;
    float4 f = *(const float4*)(src + (base - (size_t)r * WELEMS));
    ushort4 o = make_ushort4(f2bf(f.x), f2bf(f.y), f2bf(f.z), f2bf(f.w));
    *(ushort4*)(dst + base) = o;
}

// ---------------------------------------------------------------- GEMM
// C[M,N] = A[M,K] * B[N,K]^T  (both K-major, bf16), fp32 accumulate.
// 1-D grid; supertile raster: 8 consecutive blocks span 8 bm at one bn, so
// each XCD (bid%8) keeps a single A panel L2-resident while B is co-read.
// 128x128 tile, BK=64, 4 waves 2x2, each wave 64x64 via 2x2 MFMA 32x32x16.
// LDS 16B-chunk slot c' of row r holds global chunk c = c' ^ (r&7).
// MODE 0: C = acc + bias           -> bf16 out
// MODE 1: C = acc + bias + resid16 -> bf16 out (resid bf16)
template<int MODE>
__global__ __launch_bounds__(256, 3) void gemm_bt(
    const u16* __restrict__ A, const u16* __restrict__ B,
    const float* __restrict__ bias, u16* __restrict__ Cout,
    const u16* __restrict__ resid, int M, int N, int K)
{
    __shared__ __align__(16) u16 As[128 * 64];
    __shared__ __align__(16) u16 Bs[128 * 64];

    const int tid  = threadIdx.x;
    const int lane = tid & 63;
    const int wave = tid >> 6;

    // supertile decomposition: GROUP_M = 8 along bm, bm-fastest
    const int num_bn = N >> 7;
    const int rem = blockIdx.x % (num_bn << 3);
    const int bn  = rem >> 3;
    const int bm  = ((blockIdx.x / (num_bn << 3)) << 3) + (rem & 7);

    const int srow = tid >> 3;                        // 0..31
    const int sc   = (tid & 7) ^ (srow & 7);          // swizzle key = row&7
    const u16* Ag = A + (size_t)(bm * 128 + srow) * K + sc * 8;
    const u16* Bg = B + (size_t)(bn * 128 + srow) * K + sc * 8;
    const size_t row32 = (size_t)32 * K;
    u16* asd = As + wave * 512;                       // +r*2048 per round
    u16* bsd = Bs + wave * 512;

    const int rl = lane & 31;      // row within 32-tile (A: m, B: n)
    const int h  = lane >> 5;      // k-half of 16-k step
    const int swz = rl & 7;        // read-side swizzle key
    const int wm = (wave >> 1) * 64;
    const int wn = (wave & 1) * 64;

    f32x16 acc[2][2] = {};

    for (int kb = 0; kb < K; kb += 64) {
        __syncthreads();
#pragma unroll
        for (int r = 0; r < 4; ++r) {
            gl2lds16(Ag + kb + r * row32, asd + r * 2048);
            gl2lds16(Bg + kb + r * row32, bsd + r * 2048);
        }
        __syncthreads();

#pragma unroll
        for (int s = 0; s < 4; ++s) {                 // four 16-k steps
            const int ch = ((s * 2 + h) ^ swz) * 8;   // u16 offset of chunk
            bf16x8 a0 = *(const bf16x8*)(As + (wm      + rl) * 64 + ch);
            bf16x8 a1 = *(const bf16x8*)(As + (wm + 32 + rl) * 64 + ch);
            bf16x8 b0 = *(const bf16x8*)(Bs + (wn      + rl) * 64 + ch);
            bf16x8 b1 = *(const bf16x8*)(Bs + (wn + 32 + rl) * 64 + ch);
            acc[0][0] = __builtin_amdgcn_mfma_f32_32x32x16_bf16(a0, b0, acc[0][0], 0, 0, 0);
            acc[0][1] = __builtin_amdgcn_mfma_f32_32x32x16_bf16(a0, b1, acc[0][1], 0, 0, 0);
            acc[1][0] = __builtin_amdgcn_mfma_f32_32x32x16_bf16(a1, b0, acc[1][0], 0, 0, 0);
            acc[1][1] = __builtin_amdgcn_mfma_f32_32x32x16_bf16(a1, b1, acc[1][1], 0, 0, 0);
        }
    }

    // epilogue: C/D layout col = lane&31, row = (reg&3) + 8*(reg>>2) + 4*h
#pragma unroll
    for (int mt = 0; mt < 2; ++mt) {
#pragma unroll
        for (int nt = 0; nt < 2; ++nt) {
            const int gn = bn * 128 + wn + nt * 32 + rl;
            const float bv = bias[gn];
#pragma unroll
            for (int reg = 0; reg < 16; ++reg) {
                const int gm = bm * 128 + wm + mt * 32 +
                               (reg & 3) + 8 * (reg >> 2) + 4 * h;
                const size_t idx = (size_t)gm * N + gn;
                float v = acc[mt][nt][reg] + bv;
                if constexpr (MODE == 1) v += bf2f(resid[idx]);
                Cout[idx] = f2bf(v);
            }
        }
    }
}

// ---------------------------------------------------------------- attention
// One block per token. q/k/v staged as [16 heads][148 floats] (pad 144->148:
// row-to-row bank offset = 20 -> strided head reads conflict-free).
// S = QK^T/12 over d=144 per head pair, softmax over m (stored transposed),
// O-step: 144 tasks of (4 cols x 4 heads) with float4 W and V reads.
#define HROW 148
__global__ __launch_bounds__(256) void attn_headmix(
    const u16* __restrict__ QKV, u16* __restrict__ Aout)
{
    __shared__ __align__(16) float qs[16 * HROW];
    __shared__ __align__(16) float ks[16 * HROW];
    __shared__ __align__(16) float vs[16 * HROW];
    __shared__ __align__(16) float wsmT[256];   // wsmT[m][n]

    const int tid = threadIdx.x;
    const int t   = blockIdx.x;
    const float fpos = (float)(t & SEQ_MASK);
    const u16* row = QKV + (size_t)t * NQKV;

    const float OMEGA_C = -2.0f * 13.287712379549449f / 2304.0f; // -2*log2(1e4)/d
    const float INV2PI  = 0.15915494309189535f;

    for (int c = tid; c < 864; c += 256) {       // 864 chunks of 8 bf16
        uint4 raw = *(const uint4*)(row + c * 8);
        float f[8];
        f[0] = bf2f(raw.x & 0xffff); f[1] = bf2f(raw.x >> 16);
        f[2] = bf2f(raw.y & 0xffff); f[3] = bf2f(raw.y >> 16);
        f[4] = bf2f(raw.z & 0xffff); f[5] = bf2f(raw.z >> 16);
        f[6] = bf2f(raw.w & 0xffff); f[7] = bf2f(raw.w >> 16);
        if (c < 576) {                            // q or k chunk -> RoPE
            const int cc = (c < 288) ? c : c - 288;
            const int p0 = cc * 4;                // pair index in full 2304
#pragma unroll
            for (int jp = 0; jp < 4; ++jp) {
                float omega = exp2f((float)(p0 + jp) * OMEGA_C);
                float rr = fpos * omega * INV2PI;
                rr -= floorf(rr);
                float sn = __builtin_amdgcn_sinf(rr);
                float cs = __builtin_amdgcn_cosf(rr);
                float x0 = f[2 * jp], x1 = f[2 * jp + 1];
                f[2 * jp]     = cs * x0 - sn * x1;
                f[2 * jp + 1] = sn * x0 + cs * x1;
            }
            const int hr = cc / 18, col = (cc - hr * 18) * 8;  // 18 chunks/head
            float* dst = ((c < 288) ? qs : ks) + hr * HROW + col;
            *(float4*)(dst)     = make_float4(f[0], f[1], f[2], f[3]);
            *(float4*)(dst + 4) = make_float4(f[4], f[5], f[6], f[7]);
        } else {
            const int cv = c - 576;
            const int hr = cv / 18, col = (cv - hr * 18) * 8;
            float* dst = vs + hr * HROW + col;
            *(float4*)(dst)     = make_float4(f[0], f[1], f[2], f[3]);
            *(float4*)(dst + 4) = make_float4(f[4], f[5], f[6], f[7]);
        }
    }
    __syncthreads();

    // S[n][m]: thread (n = tid>>4, m = tid&15)
    const int n = tid >> 4, m = tid & 15;
    const float* qr = qs + n * HROW;
    const float* kr = ks + m * HROW;
    float s = 0.f;
#pragma unroll
    for (int d = 0; d < 144; d += 4) {
        float4 qv = *(const float4*)(qr + d);
        float4 kv = *(const float4*)(kr + d);
        s += qv.x * kv.x + qv.y * kv.y + qv.z * kv.z + qv.w * kv.w;
    }
    s *= (1.0f / 12.0f);                         // 1/sqrt(144)

    float mx = s;
#pragma unroll
    for (int off = 8; off >= 1; off >>= 1) mx = fmaxf(mx, __shfl_xor(mx, off));
    float e = __expf(s - mx);
    float sum = e;
#pragma unroll
    for (int off = 8; off >= 1; off >>= 1) sum += __shfl_xor(sum, off);
    wsmT[m * 16 + n] = e / sum;                  // transposed store
    __syncthreads();

    // O: task = (col4 = 0..35, nq = 0..3); 144 active threads
    if (tid < 144) {
        const int col4 = tid % 36;
        const int nq   = tid / 36;
        const int oc   = col4 * 4;
        float4 a0 = {0,0,0,0}, a1 = {0,0,0,0}, a2 = {0,0,0,0}, a3 = {0,0,0,0};
#pragma unroll
        for (int mm = 0; mm < 16; ++mm) {
            float4 w4 = *(const float4*)(wsmT + mm * 16 + nq * 4);
            float4 v4 = *(const float4*)(vs + mm * HROW + oc);
            a0.x += w4.x * v4.x; a0.y += w4.x * v4.y; a0.z += w4.x * v4.z; a0.w += w4.x * v4.w;
            a1.x += w4.y * v4.x; a1.y += w4.y * v4.y; a1.z += w4.y * v4.z; a1.w += w4.y * v4.w;
            a2.x += w4.z * v4.x; a2.y += w4.z * v4.y; a2.z += w4.z * v4.z; a2.w += w4.z * v4.w;
            a3.x += w4.w * v4.x; a3.y += w4.w * v4.y; a3.z += w4.w * v4.z; a3.w += w4.w * v4.w;
        }
        u16* orow = Aout + (size_t)t * D_HID;
        float4 accs[4] = {a0, a1, a2, a3};
#pragma unroll
        for (int i = 0; i < 4; ++i) {
            const int nn = nq * 4 + i;
            ushort4 o = make_ushort4(f2bf(accs[i].x), f2bf(accs[i].y),
                                     f2bf(accs[i].z), f2bf(accs[i].w));
            *(ushort4*)(orow + nn * 144 + oc) = o;
        }
    }
}

// ---------------------------------------------------------------- layernorm
__global__ __launch_bounds__(256) void ln_kernel(
    const u16* __restrict__ Y, const float* __restrict__ g,
    const float* __restrict__ b, float* __restrict__ out)
{
    const int tid  = threadIdx.x;
    const u16* y = Y + (size_t)blockIdx.x * D_HID;
    float v[9];
    float s = 0.f, s2 = 0.f;
#pragma unroll
    for (int r = 0; r < 9; ++r) {
        v[r] = bf2f(y[tid + r * 256]);
        s += v[r]; s2 += v[r] * v[r];
    }
#pragma unroll
    for (int off = 32; off >= 1; off >>= 1) {
        s  += __shfl_xor(s, off);
        s2 += __shfl_xor(s2, off);
    }
    __shared__ float red[8];
    const int wave = tid >> 6;
    if ((tid & 63) == 0) { red[wave] = s; red[4 + wave] = s2; }
    __syncthreads();
    s  = red[0] + red[1] + red[2] + red[3];
    s2 = red[4] + red[5] + red[6] + red[7];
    const float inv_n = 1.0f / 2304.0f;
    float mu  = s * inv_n;
    float var = fmaxf(s2 * inv_n - mu * mu, 0.f);
    float inv = rsqrtf(var + 1e-5f);
    float* orow = out + (size_t)blockIdx.x * D_HID;
#pragma unroll
    for (int r = 0; r < 9; ++r) {
        int c = tid + r * 256;
        orow[c] = (v[r] - mu) * inv * g[c] + b[c];
    }
}

// ---------------------------------------------------------------- launch
extern "C" void kernel_launch(void* const* d_in, const int* in_sizes, int n_in,
                              void* d_out, int out_size, void* d_ws, size_t ws_size,
                              hipStream_t stream)
{
    const float* x   = (const float*)d_in[0];
    const float* wq  = (const float*)d_in[1];
    const float* bq  = (const float*)d_in[2];
    const float* wk  = (const float*)d_in[3];
    const float* bk  = (const float*)d_in[4];
    const float* wv  = (const float*)d_in[5];
    const float* bv  = (const float*)d_in[6];
    const float* wo  = (const float*)d_in[7];
    const float* bo  = (const float*)d_in[8];
    const float* lng = (const float*)d_in[9];
    const float* lnb = (const float*)d_in[10];

    char* ws = (char*)d_ws;
    size_t off = 0;
    auto alloc = [&](size_t bytes) {
        void* p = ws + off;
        off += (bytes + 255) & ~(size_t)255;
        return p;
    };
    u16*   xb   = (u16*)alloc((size_t)NTOK * D_HID * 2);
    u16*   wqkv = (u16*)alloc((size_t)(NQKV + D_HID) * D_HID * 2);
    u16*   wob  = wqkv + (size_t)NQKV * D_HID;
    float* bqkv = (float*)alloc((size_t)NQKV * 4);
    u16*   qkv  = (u16*)alloc((size_t)NTOK * NQKV * 2);
    u16*   aout = (u16*)alloc((size_t)NTOK * D_HID * 2);
    u16*   ybuf = qkv;  // QKV dead after attention; reuse for bf16 y

    cvt_f32_bf16<<<NTOK * D_HID / 1024, 256, 0, stream>>>(x, xb);
    cvt_weights<<<4 * WELEMS / 1024, 256, 0, stream>>>(wq, wk, wv, wo, wqkv,
                                                       bq, bk, bv, bqkv);
    gemm_bt<0><<<(NQKV / 128) * (NTOK / 128), 256, 0, stream>>>(
        xb, wqkv, bqkv, qkv, nullptr, NTOK, NQKV, D_HID);
    attn_headmix<<<NTOK, 256, 0, stream>>>(qkv, aout);
    gemm_bt<1><<<(D_HID / 128) * (NTOK / 128), 256, 0, stream>>>(
        aout, wob, bo, ybuf, xb, NTOK, D_HID, D_HID);
    ln_kernel<<<NTOK, 256, 0, stream>>>(ybuf, lng, lnb, (float*)d_out);
}